// Round 6
// baseline (245.415 us; speedup 1.0000x reference)
//
#include <hip/hip_runtime.h>

#define N_SEQ 4140
#define NP    4160          // padded N (multiple of 32)
#define C_IN  256
#define HEADS 8
#define NT32  130           // ceil(4140/32) KV tiles
#define HN    (HEADS * N_SEQ)
#define LOG2E 1.4426950408889634f

typedef _Float16 f16x8 __attribute__((ext_vector_type(8)));
typedef float    f32x16 __attribute__((ext_vector_type(16)));

__device__ inline unsigned short f16b(float x) {
    union { _Float16 h; unsigned short s; } c;
    c.h = (_Float16)x;
    return c.s;
}
__device__ inline unsigned pack2h(float lo, float hi) {
    union { _Float16 h[2]; unsigned u; } c;
    c.h[0] = (_Float16)lo;      // element 0 = low 16 bits
    c.h[1] = (_Float16)hi;      // element 1 = high 16 bits
    return c.u;
}

// ---------------------------------------------------------------------------
// Pad init: lwp[0..4159] = log_qw*log2(e) or -1e30; zero V pad columns.
// ---------------------------------------------------------------------------
__global__ __launch_bounds__(256) void init_pad_kernel(
    const float* __restrict__ log_qw, float* __restrict__ lwp,
    unsigned short* __restrict__ vb)
{
    const int i = blockIdx.x * 256 + threadIdx.x;
    if (i < NP) lwp[i] = (i < N_SEQ) ? log_qw[i] * LOG2E : -1e30f;
    if (i < C_IN * (NP - N_SEQ)) {
        const int c = i / (NP - N_SEQ);
        const int col = N_SEQ + i % (NP - N_SEQ);
        vb[(size_t)c * NP + col] = 0;
    }
}

// ---------------------------------------------------------------------------
// QKV: f32 GEMM, f16 outputs. 8 channels x 4 n-positions per thread.
// q,k -> [h][n][32] ; v -> [h*32+d][n]
// grid: (ceil(N/1024), 96), blockIdx.y*8 selects 8 channels in [0,768)
// ---------------------------------------------------------------------------
__global__ __launch_bounds__(256) void qkv_kernel(
    const float* __restrict__ x,
    const float* __restrict__ q_w, const float* __restrict__ q_b,
    const float* __restrict__ k_w, const float* __restrict__ k_b,
    const float* __restrict__ v_w, const float* __restrict__ v_b,
    unsigned short* __restrict__ qo, unsigned short* __restrict__ ko,
    unsigned short* __restrict__ vo)
{
    const int n0 = blockIdx.x * 1024 + threadIdx.x;
    const int cc0 = blockIdx.y * 8;
    const int mat = cc0 >> 8;          // 0=q, 1=k, 2=v
    const int row0 = cc0 & 255;
    const float* w; const float* b;
    if (mat == 0)      { w = q_w; b = q_b; }
    else if (mat == 1) { w = k_w; b = k_b; }
    else               { w = v_w; b = v_b; }

    int  nn[4]; bool val[4];
#pragma unroll
    for (int i = 0; i < 4; ++i) {
        const int n = n0 + i * 256;
        val[i] = n < N_SEQ;
        nn[i] = val[i] ? n : 0;
    }

    float acc[4][8];
#pragma unroll
    for (int i = 0; i < 4; ++i)
#pragma unroll
        for (int j = 0; j < 8; ++j) acc[i][j] = b[row0 + j];

    const float* wr = w + (size_t)row0 * C_IN;
#pragma unroll 4
    for (int c = 0; c < C_IN; ++c) {
        float xv[4];
#pragma unroll
        for (int i = 0; i < 4; ++i) xv[i] = x[(size_t)c * N_SEQ + nn[i]];
#pragma unroll
        for (int j = 0; j < 8; ++j) {
            const float wv = wr[j * C_IN + c];
#pragma unroll
            for (int i = 0; i < 4; ++i)
                acc[i][j] = fmaf(wv, xv[i], acc[i][j]);
        }
    }

    if (mat < 2) {
        const int h = row0 >> 5;
        const int d0 = row0 & 31;
        unsigned short* base = (mat ? ko : qo);
#pragma unroll
        for (int i = 0; i < 4; ++i) {
            if (!val[i]) continue;
            union { unsigned short s[8]; uint4 q; } pk;
#pragma unroll
            for (int j = 0; j < 8; ++j) pk.s[j] = f16b(acc[i][j]);
            *(uint4*)(base + ((size_t)(h * NP + nn[i])) * 32 + d0) = pk.q;
        }
    } else {
#pragma unroll
        for (int i = 0; i < 4; ++i) {
            if (!val[i]) continue;
#pragma unroll
            for (int j = 0; j < 8; ++j)
                vo[(size_t)(row0 + j) * NP + nn[i]] = f16b(acc[i][j]);
        }
    }
}

// ---------------------------------------------------------------------------
// MFMA flash attention (f16, log2-domain softmax, defer-max). 4 waves/block,
// wave = one (head, q-tile of 32) job. Swapped QK^T: S[key][q] = mfma(K, Q);
// PV: O^T[d][q] = mfma(V^T, Pt). grid: (260, nz) x 256 threads.
// ---------------------------------------------------------------------------
__global__ __launch_bounds__(256) void attn_mfma_kernel(
    const unsigned short* __restrict__ qb, const unsigned short* __restrict__ kb,
    const unsigned short* __restrict__ vb, const float* __restrict__ lwp,
    float* __restrict__ pm, float* __restrict__ pl, float* __restrict__ pacc,
    int tiles_per_z)
{
    const int tid = threadIdx.x;
    const int wid = tid >> 6;
    const int lane = tid & 63;
    const int col = lane & 31;          // query column (QK) / d row (PV)
    const int hi = lane >> 5;
    const int job = blockIdx.x * 4 + wid;   // 0..1039
    const int h = job / NT32;
    const int qt = job % NT32;
    const int z = blockIdx.y;

    const int qrow = qt * 32 + col;
    const unsigned short* qp = qb + ((size_t)(h * NP + qrow)) * 32 + hi * 8;
    const f16x8 qf0 = *(const f16x8*)(const void*)(qp);
    const f16x8 qf1 = *(const f16x8*)(const void*)(qp + 16);

    f32x16 o;
#pragma unroll
    for (int r = 0; r < 16; ++r) o[r] = 0.f;
    float m = -1e30f, lsum = 0.f;
    const float scale2 = 0.17677669529663687f * LOG2E;   // 1/sqrt(32) * log2e

    const int t0 = z * tiles_per_z;
    const int t1 = min(NT32, t0 + tiles_per_z);
    const unsigned short* kbase = kb + (size_t)h * NP * 32;
    const unsigned short* vrow  = vb + ((size_t)(h * 32 + col)) * NP;

    for (int t = t0; t < t1; ++t) {
        const int k0 = t * 32;
        const unsigned short* kp = kbase + (size_t)(k0 + col) * 32 + hi * 8;
        const f16x8 ka0 = *(const f16x8*)(const void*)(kp);
        const f16x8 ka1 = *(const f16x8*)(const void*)(kp + 16);
        const f16x8 va0 = *(const f16x8*)(const void*)(vrow + k0 + hi * 8);
        const f16x8 va1 = *(const f16x8*)(const void*)(vrow + k0 + 16 + hi * 8);
        const float* lwb = lwp + k0 + 4 * hi;

        f32x16 s;
#pragma unroll
        for (int r = 0; r < 16; ++r) s[r] = 0.f;
        s = __builtin_amdgcn_mfma_f32_32x32x16_f16(ka0, qf0, s, 0, 0, 0);
        s = __builtin_amdgcn_mfma_f32_32x32x16_f16(ka1, qf1, s, 0, 0, 0);

        float p[16];
#pragma unroll
        for (int r = 0; r < 16; ++r)
            p[r] = fmaf(s[r], scale2, lwb[(r & 3) + 8 * (r >> 2)]);

        // pairwise max tree (depth 4) + cross-half
        float x0 = fmaxf(p[0], p[1]),   x1 = fmaxf(p[2], p[3]);
        float x2 = fmaxf(p[4], p[5]),   x3 = fmaxf(p[6], p[7]);
        float x4 = fmaxf(p[8], p[9]),   x5 = fmaxf(p[10], p[11]);
        float x6 = fmaxf(p[12], p[13]), x7 = fmaxf(p[14], p[15]);
        x0 = fmaxf(x0, x1); x2 = fmaxf(x2, x3);
        x4 = fmaxf(x4, x5); x6 = fmaxf(x6, x7);
        float cmax = fmaxf(fmaxf(x0, x2), fmaxf(x4, x6));
        cmax = fmaxf(cmax, __shfl_xor(cmax, 32));

        // defer-max: only rescale when max grew past threshold (log2 domain)
        if (!__all(cmax - m <= 8.0f)) {
            const float mnew = fmaxf(m, cmax);
            const float esc = __builtin_amdgcn_exp2f(m - mnew);
            lsum *= esc;
#pragma unroll
            for (int r = 0; r < 16; ++r) o[r] *= esc;
            m = mnew;
        }

#pragma unroll
        for (int r = 0; r < 16; ++r) p[r] = __builtin_amdgcn_exp2f(p[r] - m);
        // pairwise sum tree
        {
            float s0 = (p[0] + p[1]) + (p[2] + p[3]);
            float s1 = (p[4] + p[5]) + (p[6] + p[7]);
            float s2 = (p[8] + p[9]) + (p[10] + p[11]);
            float s3 = (p[12] + p[13]) + (p[14] + p[15]);
            lsum += (s0 + s1) + (s2 + s3);
        }

        // pack P -> f16 B-frags (B[k=key][col=q]); partner exchange via shfl.
        union U { unsigned u[4]; f16x8 v; };
        const unsigned a0 = pack2h(p[0], p[1]),  b0 = pack2h(p[2], p[3]);
        const unsigned c0 = pack2h(p[4], p[5]),  d0 = pack2h(p[6], p[7]);
        const unsigned as = __shfl_xor(a0, 32), bs = __shfl_xor(b0, 32);
        const unsigned cs = __shfl_xor(c0, 32), ds = __shfl_xor(d0, 32);
        U pb0;
        pb0.u[0] = hi ? cs : a0;
        pb0.u[1] = hi ? ds : b0;
        pb0.u[2] = hi ? c0 : as;
        pb0.u[3] = hi ? d0 : bs;
        o = __builtin_amdgcn_mfma_f32_32x32x16_f16(va0, pb0.v, o, 0, 0, 0);

        const unsigned e0 = pack2h(p[8], p[9]),   f0 = pack2h(p[10], p[11]);
        const unsigned g0 = pack2h(p[12], p[13]), h0 = pack2h(p[14], p[15]);
        const unsigned es = __shfl_xor(e0, 32), fs = __shfl_xor(f0, 32);
        const unsigned gs = __shfl_xor(g0, 32), hs = __shfl_xor(h0, 32);
        U pb1;
        pb1.u[0] = hi ? gs : e0;
        pb1.u[1] = hi ? hs : f0;
        pb1.u[2] = hi ? g0 : es;
        pb1.u[3] = hi ? h0 : fs;
        o = __builtin_amdgcn_mfma_f32_32x32x16_f16(va1, pb1.v, o, 0, 0, 0);
    }

    lsum += __shfl_xor(lsum, 32);   // combine key-halves (partner lane)

    if (qrow < N_SEQ) {
        const size_t qi = (size_t)h * N_SEQ + qrow;
        if (hi == 0) {
            pm[(size_t)z * HN + qi] = m;
            pl[(size_t)z * HN + qi] = lsum;
        }
        float* pa = pacc + ((size_t)z * HN + qi) * 32;
#pragma unroll
        for (int r = 0; r < 16; ++r)
            pa[(r & 3) + 8 * (r >> 2) + 4 * hi] = o[r];
    }
}

// ---------------------------------------------------------------------------
// Merge key-split partials -> attn_out[c][n] (channel-major, f32).
// pm is in log2 domain -> exp2f.
// ---------------------------------------------------------------------------
__global__ __launch_bounds__(256) void merge_kernel(
    const float* __restrict__ pm, const float* __restrict__ pl,
    const float* __restrict__ pacc, float* __restrict__ attn_out, int nz)
{
    const int idx = blockIdx.x * 256 + threadIdx.x;
    if (idx >= HN) return;
    const int h = idx / N_SEQ;
    const int n = idx - h * N_SEQ;

    float mg = pm[idx];
    for (int zz = 1; zz < nz; ++zz) mg = fmaxf(mg, pm[(size_t)zz * HN + idx]);

    float lg = 0.f;
    float acc[32];
#pragma unroll
    for (int d = 0; d < 32; ++d) acc[d] = 0.f;
    for (int zz = 0; zz < nz; ++zz) {
        const float e = exp2f(pm[(size_t)zz * HN + idx] - mg);
        lg += pl[(size_t)zz * HN + idx] * e;
        const float* pa = pacc + ((size_t)zz * HN + idx) * 32;
#pragma unroll
        for (int d = 0; d < 32; ++d) acc[d] = fmaf(pa[d], e, acc[d]);
    }
    const float inv = 1.0f / lg;
#pragma unroll
    for (int d = 0; d < 32; ++d)
        attn_out[(size_t)(h * 32 + d) * N_SEQ + n] = acc[d] * inv;
}

// ---------------------------------------------------------------------------
// Proj: out[k][n] = sum_c p_w[k][c] * attn_out[c][n] + p_b[k]  (f32)
// 8 channels x 4 n-positions per thread. grid: (ceil(N/1024), 32)
// ---------------------------------------------------------------------------
__global__ __launch_bounds__(256) void proj_kernel(
    const float* __restrict__ x, const float* __restrict__ p_w,
    const float* __restrict__ p_b, float* __restrict__ out)
{
    const int n0 = blockIdx.x * 1024 + threadIdx.x;
    const int row0 = blockIdx.y * 8;

    int  nn[4]; bool val[4];
#pragma unroll
    for (int i = 0; i < 4; ++i) {
        const int n = n0 + i * 256;
        val[i] = n < N_SEQ;
        nn[i] = val[i] ? n : 0;
    }

    float acc[4][8];
#pragma unroll
    for (int i = 0; i < 4; ++i)
#pragma unroll
        for (int j = 0; j < 8; ++j) acc[i][j] = p_b[row0 + j];

    const float* wr = p_w + (size_t)row0 * C_IN;
#pragma unroll 4
    for (int c = 0; c < C_IN; ++c) {
        float xv[4];
#pragma unroll
        for (int i = 0; i < 4; ++i) xv[i] = x[(size_t)c * N_SEQ + nn[i]];
#pragma unroll
        for (int j = 0; j < 8; ++j) {
            const float wv = wr[j * C_IN + c];
#pragma unroll
            for (int i = 0; i < 4; ++i)
                acc[i][j] = fmaf(wv, xv[i], acc[i][j]);
        }
    }

#pragma unroll
    for (int i = 0; i < 4; ++i) {
        if (!val[i]) continue;
#pragma unroll
        for (int j = 0; j < 8; ++j)
            out[(size_t)(row0 + j) * N_SEQ + nn[i]] = acc[i][j];
    }
}

extern "C" void kernel_launch(void* const* d_in, const int* in_sizes, int n_in,
                              void* d_out, int out_size, void* d_ws, size_t ws_size,
                              hipStream_t stream) {
    const float* query  = (const float*)d_in[0];
    const float* q_w    = (const float*)d_in[1];
    const float* q_b    = (const float*)d_in[2];
    const float* k_w    = (const float*)d_in[3];
    const float* k_b    = (const float*)d_in[4];
    const float* v_w    = (const float*)d_in[5];
    const float* v_b    = (const float*)d_in[6];
    const float* p_w    = (const float*)d_in[7];
    const float* p_b    = (const float*)d_in[8];
    const float* log_qw = (const float*)d_in[9];

    const size_t BFELEM = (size_t)HEADS * NP * 32;   // 1,064,960 f16 per buf

    // ws layout
    unsigned short* qb = (unsigned short*)d_ws;
    unsigned short* kb = qb + BFELEM;
    unsigned short* vb = kb + BFELEM;
    float* lwp      = (float*)(vb + BFELEM);
    float* attn_out = lwp + NP;
    float* pm       = attn_out + (size_t)C_IN * N_SEQ;

    const size_t base_bytes = (size_t)((char*)pm - (char*)d_ws);
    const size_t per_z = (size_t)HN * 34 * sizeof(float);
    int nz = 1;
    if      (ws_size >= base_bytes + 8 * per_z) nz = 8;
    else if (ws_size >= base_bytes + 4 * per_z) nz = 4;
    else if (ws_size >= base_bytes + 2 * per_z) nz = 2;
    const int tiles_per_z = (NT32 + nz - 1) / nz;

    float* pl   = pm + (size_t)nz * HN;
    float* pacc = pl + (size_t)nz * HN;

    init_pad_kernel<<<dim3(20), 256, 0, stream>>>(log_qw, lwp, vb);

    qkv_kernel<<<dim3(5, 96), 256, 0, stream>>>(
        query, q_w, q_b, k_w, k_b, v_w, v_b, qb, kb, vb);

    attn_mfma_kernel<<<dim3(260, nz), 256, 0, stream>>>(
        qb, kb, vb, lwp, pm, pl, pacc, tiles_per_z);

    merge_kernel<<<dim3((HN + 255) / 256), 256, 0, stream>>>(
        pm, pl, pacc, attn_out, nz);

    proj_kernel<<<dim3(5, 32), 256, 0, stream>>>(
        attn_out, p_w, p_b, (float*)d_out);
}

// Round 7
// 174.694 us; speedup vs baseline: 1.4048x; 1.4048x over previous
//
#include <hip/hip_runtime.h>

#define N_SEQ 4140
#define NP    4160          // padded N (130*32)
#define C_IN  256
#define HEADS 8
#define NT32  130
#define HN    (HEADS * N_SEQ)
#define LOG2E 1.4426950408889634f
#define SCALE2 (0.17677669529663687f * LOG2E)   // (1/sqrt(32)) * log2e
#define INVSCALE 5.656854249492381f             // sqrt(32)

typedef _Float16 f16x8 __attribute__((ext_vector_type(8)));
typedef float    f32x16 __attribute__((ext_vector_type(16)));

__device__ inline unsigned short f16b(float x) {
    union { _Float16 h; unsigned short s; } c;
    c.h = (_Float16)x;
    return c.s;
}
__device__ inline unsigned pack2h(float lo, float hi) {
    union { _Float16 h[2]; unsigned u; } c;
    c.h[0] = (_Float16)lo;
    c.h[1] = (_Float16)hi;
    return c.u;
}
// v_permlane32_swap_b32: a'[0:31]=a[0:31], a'[32:63]=b[0:31];
//                        b'[0:31]=a[32:63], b'[32:63]=b[32:63]
__device__ inline void permswap(unsigned &a, unsigned &b) {
    asm volatile("v_permlane32_swap_b32 %0, %1" : "+v"(a), "+v"(b));
}

// ---------------------------------------------------------------------------
// convert_x: x[c][n] f32 -> xt[n][c] f16 (zero-pad rows n>=N_SEQ). LDS transpose.
// grid: (130, 8) x 256
// ---------------------------------------------------------------------------
__global__ __launch_bounds__(256) void convert_x(
    const float* __restrict__ x, unsigned short* __restrict__ xt)
{
    __shared__ unsigned short tile[32][33];
    const int tx = threadIdx.x & 31, ty = threadIdx.x >> 5;   // 32 x 8
    const int n0 = blockIdx.x * 32, c0 = blockIdx.y * 32;
#pragma unroll
    for (int i = 0; i < 4; ++i) {
        const int c = c0 + ty * 4 + i;
        const int n = n0 + tx;
        const float v = (n < N_SEQ) ? x[(size_t)c * N_SEQ + n] : 0.f;
        tile[tx][ty * 4 + i] = f16b(v);
    }
    __syncthreads();
#pragma unroll
    for (int i = 0; i < 4; ++i) {
        const int nl = ty * 4 + i;
        xt[(size_t)(n0 + nl) * C_IN + c0 + tx] = tile[nl][tx];
    }
}

// ---------------------------------------------------------------------------
// init_misc: lw2 (log_qw/scale, pad -1e30), wf (q/k/v weights f16), pwf (p_w f16)
// ---------------------------------------------------------------------------
__global__ __launch_bounds__(256) void init_misc(
    const float* __restrict__ log_qw,
    const float* __restrict__ q_w, const float* __restrict__ k_w,
    const float* __restrict__ v_w, const float* __restrict__ p_w,
    float* __restrict__ lw2, unsigned short* __restrict__ wf,
    unsigned short* __restrict__ pwf)
{
    const int i = blockIdx.x * 256 + threadIdx.x;
    if (i < NP) lw2[i] = (i < N_SEQ) ? log_qw[i] * INVSCALE : -1e30f;
    if (i < 65536)       wf[i] = f16b(q_w[i]);
    else if (i < 131072) wf[i] = f16b(k_w[i - 65536]);
    else if (i < 196608) wf[i] = f16b(v_w[i - 131072]);
    if (i < 65536) pwf[i] = f16b(p_w[i]);
}

// ---------------------------------------------------------------------------
// qkv_mfma: 24 oc-tiles x 130 n-tiles, 1 wave each, K=256 (16 mfma).
// ot 0..7: q (A=xt rows n, B=w_q)   -> qo[h][n][32]
// ot 8..15: k                        -> ko[h][n][32]
// ot 16..23: v (A=w_v rows d, B=xt) -> vo[((h*130+t)*32+d)*32+klocal]
// grid: 780 x 256
// ---------------------------------------------------------------------------
__global__ __launch_bounds__(256) void qkv_mfma(
    const unsigned short* __restrict__ xt, const unsigned short* __restrict__ wf,
    const float* __restrict__ q_b, const float* __restrict__ k_b,
    const float* __restrict__ v_b,
    unsigned short* __restrict__ qo, unsigned short* __restrict__ ko,
    unsigned short* __restrict__ vo)
{
    const int tid = threadIdx.x, wid = tid >> 6, lane = tid & 63;
    const int col = lane & 31, hi = lane >> 5;
    const int tile = blockIdx.x * 4 + wid;       // 0..3119
    const int ot = tile / NT32, nt = tile % NT32;
    const int n0 = nt * 32;
    const bool vmode = (ot >= 16);

    const unsigned short* arow;
    const unsigned short* brow;
    if (!vmode) {
        arow = xt + (size_t)(n0 + col) * C_IN + hi * 8;
        brow = wf + (size_t)(ot * 32 + col) * C_IN + hi * 8;
    } else {
        arow = wf + (size_t)(512 + (ot - 16) * 32 + col) * C_IN + hi * 8;
        brow = xt + (size_t)(n0 + col) * C_IN + hi * 8;
    }

    f32x16 acc;
    if (!vmode) {
        const float bias = (ot < 8) ? q_b[ot * 32 + col] : k_b[(ot - 8) * 32 + col];
#pragma unroll
        for (int r = 0; r < 16; ++r) acc[r] = bias;
    } else {
        const float* vb4 = v_b + (ot - 16) * 32 + 4 * hi;
        const float4 b0 = *(const float4*)(vb4);
        const float4 b1 = *(const float4*)(vb4 + 8);
        const float4 b2 = *(const float4*)(vb4 + 16);
        const float4 b3 = *(const float4*)(vb4 + 24);
        acc[0]=b0.x; acc[1]=b0.y; acc[2]=b0.z; acc[3]=b0.w;
        acc[4]=b1.x; acc[5]=b1.y; acc[6]=b1.z; acc[7]=b1.w;
        acc[8]=b2.x; acc[9]=b2.y; acc[10]=b2.z; acc[11]=b2.w;
        acc[12]=b3.x; acc[13]=b3.y; acc[14]=b3.z; acc[15]=b3.w;
    }

#pragma unroll
    for (int t = 0; t < 16; ++t) {
        const f16x8 af = *(const f16x8*)(const void*)(arow + t * 16);
        const f16x8 bf = *(const f16x8*)(const void*)(brow + t * 16);
        acc = __builtin_amdgcn_mfma_f32_32x32x16_f16(af, bf, acc, 0, 0, 0);
    }

    if (!vmode) {
        unsigned short* dst = (ot < 8) ? qo : ko;
        const int h = ot & 7;
#pragma unroll
        for (int r = 0; r < 16; ++r) {
            const int n = n0 + (r & 3) + 8 * (r >> 2) + 4 * hi;
            dst[(size_t)(h * NP + n) * 32 + col] = f16b(acc[r]);
        }
    } else {
        const int h = ot - 16;
#pragma unroll
        for (int r = 0; r < 16; ++r) {
            const int d = (r & 3) + 8 * (r >> 2) + 4 * hi;
            vo[((size_t)(h * NT32 + nt) * 32 + d) * 32 + col] = f16b(acc[r]);
        }
    }
}

// ---------------------------------------------------------------------------
// MFMA flash attention. Swapped QK^T, log2-domain softmax, defer-max (no
// common-path shfl), permlane32_swap pack exchange, lw folded into C-init.
// grid: (260, nz) x 256
// ---------------------------------------------------------------------------
__global__ __launch_bounds__(256) void attn_mfma_kernel(
    const unsigned short* __restrict__ qb, const unsigned short* __restrict__ kb,
    const unsigned short* __restrict__ vb, const float* __restrict__ lw2,
    float* __restrict__ pm, float* __restrict__ pl, float* __restrict__ pacc,
    int tiles_per_z)
{
    const int tid = threadIdx.x;
    const int wid = tid >> 6;
    const int lane = tid & 63;
    const int col = lane & 31;
    const int hi = lane >> 5;
    const int job = blockIdx.x * 4 + wid;   // 0..1039
    const int h = job / NT32;
    const int qt = job % NT32;
    const int z = blockIdx.y;

    const int qrow = qt * 32 + col;
    const unsigned short* qp = qb + ((size_t)(h * NP + qrow)) * 32 + hi * 8;
    const f16x8 qf0 = *(const f16x8*)(const void*)(qp);
    const f16x8 qf1 = *(const f16x8*)(const void*)(qp + 16);

    f32x16 o;
#pragma unroll
    for (int r = 0; r < 16; ++r) o[r] = 0.f;
    float m = -1e30f, lsum = 0.f;

    const int t0 = z * tiles_per_z;
    const int t1 = min(NT32, t0 + tiles_per_z);
    const unsigned short* kbase = kb + (size_t)h * NP * 32;
    const unsigned short* vbase = vb + (size_t)h * NT32 * 1024;

    for (int t = t0; t < t1; ++t) {
        const int k0 = t * 32;
        const unsigned short* kp = kbase + (size_t)(k0 + col) * 32 + hi * 8;
        const f16x8 ka0 = *(const f16x8*)(const void*)(kp);
        const f16x8 ka1 = *(const f16x8*)(const void*)(kp + 16);
        const unsigned short* vp = vbase + (size_t)t * 1024 + col * 32 + hi * 8;
        const f16x8 va0 = *(const f16x8*)(const void*)(vp);
        const f16x8 va1 = *(const f16x8*)(const void*)(vp + 16);

        // C-init = quadrature bias / scale (folded): p = (qk + lw/scale)*scale2
        const float* lw4 = lw2 + k0 + 4 * hi;
        const float4 w0 = *(const float4*)(lw4);
        const float4 w1 = *(const float4*)(lw4 + 8);
        const float4 w2 = *(const float4*)(lw4 + 16);
        const float4 w3 = *(const float4*)(lw4 + 24);
        f32x16 s;
        s[0]=w0.x; s[1]=w0.y; s[2]=w0.z; s[3]=w0.w;
        s[4]=w1.x; s[5]=w1.y; s[6]=w1.z; s[7]=w1.w;
        s[8]=w2.x; s[9]=w2.y; s[10]=w2.z; s[11]=w2.w;
        s[12]=w3.x; s[13]=w3.y; s[14]=w3.z; s[15]=w3.w;

        s = __builtin_amdgcn_mfma_f32_32x32x16_f16(ka0, qf0, s, 0, 0, 0);
        s = __builtin_amdgcn_mfma_f32_32x32x16_f16(ka1, qf1, s, 0, 0, 0);

        float p[16];
#pragma unroll
        for (int r = 0; r < 16; ++r) p[r] = s[r] * SCALE2;

        // lane-local max tree (no cross-half shfl in common path)
        float x0 = fmaxf(p[0], p[1]),   x1 = fmaxf(p[2], p[3]);
        float x2 = fmaxf(p[4], p[5]),   x3 = fmaxf(p[6], p[7]);
        float x4 = fmaxf(p[8], p[9]),   x5 = fmaxf(p[10], p[11]);
        float x6 = fmaxf(p[12], p[13]), x7 = fmaxf(p[14], p[15]);
        x0 = fmaxf(x0, x1); x2 = fmaxf(x2, x3);
        x4 = fmaxf(x4, x5); x6 = fmaxf(x6, x7);
        const float cmax = fmaxf(fmaxf(x0, x2), fmaxf(x4, x6));

        if (!__all(cmax - m <= 8.0f)) {        // rare: max grew
            float cw = fmaxf(cmax, __shfl_xor(cmax, 32));  // column-consistent
            const float mnew = fmaxf(m, cw);
            const float esc = __builtin_amdgcn_exp2f(m - mnew);
            lsum *= esc;
#pragma unroll
            for (int r = 0; r < 16; ++r) o[r] *= esc;
            m = mnew;
        }

#pragma unroll
        for (int r = 0; r < 16; ++r) p[r] = __builtin_amdgcn_exp2f(p[r] - m);
        {
            float s0 = (p[0] + p[1]) + (p[2] + p[3]);
            float s1 = (p[4] + p[5]) + (p[6] + p[7]);
            float s2 = (p[8] + p[9]) + (p[10] + p[11]);
            float s3 = (p[12] + p[13]) + (p[14] + p[15]);
            lsum += (s0 + s1) + (s2 + s3);
        }

        // pack + permlane exchange -> B-frags
        union U { unsigned u[4]; f16x8 v; };
        unsigned a0 = pack2h(p[0], p[1]),  b0 = pack2h(p[2], p[3]);
        unsigned c0 = pack2h(p[4], p[5]),  d0 = pack2h(p[6], p[7]);
        permswap(a0, c0);   // a0 -> u[0], c0 -> u[2]
        permswap(b0, d0);   // b0 -> u[1], d0 -> u[3]
        U pb0; pb0.u[0] = a0; pb0.u[1] = b0; pb0.u[2] = c0; pb0.u[3] = d0;
        o = __builtin_amdgcn_mfma_f32_32x32x16_f16(va0, pb0.v, o, 0, 0, 0);

        unsigned e0 = pack2h(p[8], p[9]),   f0 = pack2h(p[10], p[11]);
        unsigned g0 = pack2h(p[12], p[13]), h0 = pack2h(p[14], p[15]);
        permswap(e0, g0);
        permswap(f0, h0);
        U pb1; pb1.u[0] = e0; pb1.u[1] = f0; pb1.u[2] = g0; pb1.u[3] = h0;
        o = __builtin_amdgcn_mfma_f32_32x32x16_f16(va1, pb1.v, o, 0, 0, 0);
    }

    lsum += __shfl_xor(lsum, 32);

    if (qrow < N_SEQ) {
        const size_t qi = (size_t)h * N_SEQ + qrow;
        if (hi == 0) {
            pm[(size_t)z * HN + qi] = m;
            pl[(size_t)z * HN + qi] = lsum;
        }
        float* pa = pacc + ((size_t)z * HN + qi) * 32;
#pragma unroll
        for (int r = 0; r < 16; ++r)
            pa[(r & 3) + 8 * (r >> 2) + 4 * hi] = o[r];
    }
}

// ---------------------------------------------------------------------------
// Merge key-split partials -> at_t[n][c] (f16, proj A-operand layout)
// ---------------------------------------------------------------------------
__global__ __launch_bounds__(256) void merge_kernel(
    const float* __restrict__ pm, const float* __restrict__ pl,
    const float* __restrict__ pacc, unsigned short* __restrict__ at_t, int nz)
{
    const int idx = blockIdx.x * 256 + threadIdx.x;
    if (idx >= HN) return;
    const int h = idx / N_SEQ;
    const int n = idx - h * N_SEQ;

    float mg = pm[idx];
    for (int zz = 1; zz < nz; ++zz) mg = fmaxf(mg, pm[(size_t)zz * HN + idx]);

    float lg = 0.f;
    float acc[32];
#pragma unroll
    for (int d = 0; d < 32; ++d) acc[d] = 0.f;
    for (int zz = 0; zz < nz; ++zz) {
        const float e = exp2f(pm[(size_t)zz * HN + idx] - mg);
        lg += pl[(size_t)zz * HN + idx] * e;
        const float* pa = pacc + ((size_t)zz * HN + idx) * 32;
#pragma unroll
        for (int d = 0; d < 32; ++d) acc[d] = fmaf(pa[d], e, acc[d]);
    }
    const float inv = 1.0f / lg;
    union { unsigned short s[32]; uint4 u[4]; } ph;
#pragma unroll
    for (int d = 0; d < 32; ++d) ph.s[d] = f16b(acc[d] * inv);
    uint4* dst = (uint4*)(at_t + (size_t)n * C_IN + h * 32);
#pragma unroll
    for (int i = 0; i < 4; ++i) dst[i] = ph.u[i];
}

// ---------------------------------------------------------------------------
// proj_mfma: out[oc][n] = p_w . at + p_b.  A=pwf rows oc, B=at_t. f32 out.
// grid: 260 x 256 (8 oc-tiles x 130 n-tiles)
// ---------------------------------------------------------------------------
__global__ __launch_bounds__(256) void proj_mfma(
    const unsigned short* __restrict__ at_t, const unsigned short* __restrict__ pwf,
    const float* __restrict__ p_b, float* __restrict__ out)
{
    const int tid = threadIdx.x, wid = tid >> 6, lane = tid & 63;
    const int col = lane & 31, hi = lane >> 5;
    const int tile = blockIdx.x * 4 + wid;       // 0..1039
    const int ot = tile / NT32, nt = tile % NT32;
    const int n0 = nt * 32;

    const unsigned short* arow = pwf + (size_t)(ot * 32 + col) * C_IN + hi * 8;
    const unsigned short* brow = at_t + (size_t)(n0 + col) * C_IN + hi * 8;

    const float* pb4 = p_b + ot * 32 + 4 * hi;
    const float4 b0 = *(const float4*)(pb4);
    const float4 b1 = *(const float4*)(pb4 + 8);
    const float4 b2 = *(const float4*)(pb4 + 16);
    const float4 b3 = *(const float4*)(pb4 + 24);
    f32x16 acc;
    acc[0]=b0.x; acc[1]=b0.y; acc[2]=b0.z; acc[3]=b0.w;
    acc[4]=b1.x; acc[5]=b1.y; acc[6]=b1.z; acc[7]=b1.w;
    acc[8]=b2.x; acc[9]=b2.y; acc[10]=b2.z; acc[11]=b2.w;
    acc[12]=b3.x; acc[13]=b3.y; acc[14]=b3.z; acc[15]=b3.w;

#pragma unroll
    for (int t = 0; t < 16; ++t) {
        const f16x8 af = *(const f16x8*)(const void*)(arow + t * 16);
        const f16x8 bf = *(const f16x8*)(const void*)(brow + t * 16);
        acc = __builtin_amdgcn_mfma_f32_32x32x16_f16(af, bf, acc, 0, 0, 0);
    }

    const int n = n0 + col;
    if (n < N_SEQ) {
#pragma unroll
        for (int r = 0; r < 16; ++r) {
            const int oc = ot * 32 + (r & 3) + 8 * (r >> 2) + 4 * hi;
            out[(size_t)oc * N_SEQ + n] = acc[r];
        }
    }
}

extern "C" void kernel_launch(void* const* d_in, const int* in_sizes, int n_in,
                              void* d_out, int out_size, void* d_ws, size_t ws_size,
                              hipStream_t stream) {
    const float* query  = (const float*)d_in[0];
    const float* q_w    = (const float*)d_in[1];
    const float* q_b    = (const float*)d_in[2];
    const float* k_w    = (const float*)d_in[3];
    const float* k_b    = (const float*)d_in[4];
    const float* v_w    = (const float*)d_in[5];
    const float* v_b    = (const float*)d_in[6];
    const float* p_w    = (const float*)d_in[7];
    const float* p_b    = (const float*)d_in[8];
    const float* log_qw = (const float*)d_in[9];

    const size_t HNP32 = (size_t)HEADS * NP * 32;    // 1,064,960

    // ws layout (f16 region first)
    unsigned short* xt  = (unsigned short*)d_ws;     // NP*256
    unsigned short* qb  = xt + (size_t)NP * C_IN;    // HNP32
    unsigned short* kb  = qb + HNP32;
    unsigned short* vb  = kb + HNP32;                // tiled V
    unsigned short* wf  = vb + HNP32;                // 768*256
    unsigned short* pwf = wf + 768 * 256;            // 256*256
    float* lw2 = (float*)(pwf + 256 * 256);          // NP
    float* pm  = lw2 + NP;
    unsigned short* at_t = qb;                       // alias: qb dead after attn

    const size_t base_bytes = (size_t)((char*)pm - (char*)d_ws);
    const size_t per_z = (size_t)HN * 34 * sizeof(float);
    int nz = 1;
    if      (ws_size >= base_bytes + 8 * per_z) nz = 8;
    else if (ws_size >= base_bytes + 4 * per_z) nz = 4;
    else if (ws_size >= base_bytes + 2 * per_z) nz = 2;
    const int tiles_per_z = (NT32 + nz - 1) / nz;

    float* pl   = pm + (size_t)nz * HN;
    float* pacc = pl + (size_t)nz * HN;

    convert_x<<<dim3(NT32, 8), 256, 0, stream>>>(query, xt);

    init_misc<<<dim3(768), 256, 0, stream>>>(
        log_qw, q_w, k_w, v_w, p_w, lw2, wf, pwf);

    qkv_mfma<<<dim3(780), 256, 0, stream>>>(
        xt, wf, q_b, k_b, v_b, qb, kb, vb);

    attn_mfma_kernel<<<dim3(260, nz), 256, 0, stream>>>(
        qb, kb, vb, lw2, pm, pl, pacc, tiles_per_z);

    merge_kernel<<<dim3((HN + 255) / 256), 256, 0, stream>>>(
        pm, pl, pacc, at_t, nz);

    proj_mfma<<<dim3(260), 256, 0, stream>>>(
        at_t, pwf, p_b, (float*)d_out);
}